// Round 1
// baseline (1372.388 us; speedup 1.0000x reference)
//
#include <hip/hip_runtime.h>

// ---------------------------------------------------------------------------
// TorchGRUClassifier: 2-layer GRU (B=1024, T=256, I=153, H=128) + MLP head.
// Strategy: 64 persistent blocks x 16 batch rows; all GEMMs via
// mfma_f32_16x16x32_bf16 with fp32 state; gi0 fused (x pre-cast to bf16,
// [t][b] row-major, K padded 153->160); recurrent weights reg-resident.
// ---------------------------------------------------------------------------

typedef __bf16 bf16x8 __attribute__((ext_vector_type(8)));
typedef float  f32x4  __attribute__((ext_vector_type(4)));

#define HS 136  // LDS row stride (bf16 elems) for h tiles: 128 + 8 pad

__device__ __forceinline__ f32x4 mfma16(bf16x8 a, bf16x8 b, f32x4 c) {
    return __builtin_amdgcn_mfma_f32_16x16x32_bf16(a, b, c, 0, 0, 0);
}
__device__ __forceinline__ float sigf(float x)   { return 1.f / (1.f + __expf(-x)); }
__device__ __forceinline__ float tanhf_(float x) { return 2.f * sigf(2.f * x) - 1.f; }

// ---- prep: cast weights to bf16 (W_ih0 padded K 153->160 with zeros) ------
__global__ void prep_w_kernel(const float* __restrict__ Wih0, const float* __restrict__ Whh0,
                              const float* __restrict__ Wih1, const float* __restrict__ Whh1,
                              __bf16* __restrict__ o_ih0, __bf16* __restrict__ o_hh0,
                              __bf16* __restrict__ o_ih1, __bf16* __restrict__ o_hh1) {
    int idx = blockIdx.x * 256 + threadIdx.x;      // grid covers 384*160 = 61440
    if (idx < 384 * 160) {
        int n = idx / 160, k = idx - n * 160;
        o_ih0[idx] = (__bf16)(k < 153 ? Wih0[n * 153 + k] : 0.f);
    }
    if (idx < 384 * 128) {
        o_hh0[idx] = (__bf16)Whh0[idx];
        o_ih1[idx] = (__bf16)Wih1[idx];
        o_hh1[idx] = (__bf16)Whh1[idx];
    }
}

// ---- prep: x [b][t][153] f32  ->  xb row (t*1024+b) of 160 bf16 (zero pad) -
__global__ void cast_x_kernel(const float* __restrict__ x, __bf16* __restrict__ xb) {
    int gw   = (blockIdx.x * 256 + threadIdx.x) >> 6;   // one wave per (b,t) row
    int lane = threadIdx.x & 63;
    int b = gw >> 8, t = gw & 255;
    const float* src = x + (size_t)gw * 153;
    __bf16* dst = xb + ((size_t)t * 1024 + b) * 160;
    #pragma unroll
    for (int i0 = 0; i0 < 3; ++i0) {
        int i = i0 * 64 + lane;
        if (i < 160) dst[i] = (__bf16)(i < 153 ? src[i] : 0.f);
    }
}

// ---- fused recurrence + head ----------------------------------------------
__global__ __launch_bounds__(512, 2) void gru_fused_kernel(
    const __bf16* __restrict__ xb,
    const __bf16* __restrict__ Wih0, const __bf16* __restrict__ Whh0,
    const __bf16* __restrict__ Wih1, const __bf16* __restrict__ Whh1,
    const float* __restrict__ b_ih0, const float* __restrict__ b_hh0,
    const float* __restrict__ b_ih1, const float* __restrict__ b_hh1,
    const float* __restrict__ W1, const float* __restrict__ b1,
    const float* __restrict__ W2, const float* __restrict__ b2,
    float* __restrict__ out)
{
    __shared__ __align__(16) __bf16 h0s[16 * HS];
    __shared__ __align__(16) __bf16 h1s[16 * HS];
    __shared__ float h1f[16 * 128];
    __shared__ float hdnf[16 * 64];

    const int tid  = threadIdx.x;
    const int w    = tid >> 6;        // wave 0..7 -> owns gate cols [16w,16w+16)
    const int lane = tid & 63;
    const int q    = lane >> 4;       // quad
    const int c15  = lane & 15;
    const int c_col = w * 16 + c15;   // hidden-unit / gate column this lane owns
    const int b0   = blockIdx.x * 16; // batch row base

    // --- reg-resident B-fragments for the three K=128 matrices --------------
    // B[k=q*8+j][n=lane&15] = W[n0 + (lane&15)][ks*32 + q*8 + j]
    bf16x8 fhh0[3][4], fih1[3][4], fhh1[3][4];
    #pragma unroll
    for (int g = 0; g < 3; ++g) {
        int row = g * 128 + c_col;
        #pragma unroll
        for (int ks = 0; ks < 4; ++ks) {
            int off = row * 128 + ks * 32 + q * 8;
            fhh0[g][ks] = *(const bf16x8*)(Whh0 + off);
            fih1[g][ks] = *(const bf16x8*)(Wih1 + off);
            fhh1[g][ks] = *(const bf16x8*)(Whh1 + off);
        }
    }
    float bi0[3], bh0[3], bi1[3], bh1[3];
    #pragma unroll
    for (int g = 0; g < 3; ++g) {
        bi0[g] = b_ih0[g * 128 + c_col];
        bh0[g] = b_hh0[g * 128 + c_col];
        bi1[g] = b_ih1[g * 128 + c_col];
        bh1[g] = b_hh1[g * 128 + c_col];
    }

    // fp32 h slices this lane owns: rows q*4+r, column c_col
    float h0r[4] = {0.f, 0.f, 0.f, 0.f};
    float h1r[4] = {0.f, 0.f, 0.f, 0.f};
    for (int i = tid; i < 16 * HS; i += 512) {
        h0s[i] = (__bf16)0.f; h1s[i] = (__bf16)0.f;
    }
    __syncthreads();

    f32x4 hacc[3];            // gh (recurrent) accumulators, current half-step
    f32x4 giA[3], giB[3];     // gi0 accumulators for even t / odd t

    // phase 1: gh0 = h0 @ Whh0^T   (A-frags from h0s LDS)
    auto phase_gh0 = [&]() {
        #pragma unroll
        for (int g = 0; g < 3; ++g) hacc[g] = (f32x4){0.f, 0.f, 0.f, 0.f};
        #pragma unroll
        for (int ks = 0; ks < 4; ++ks) {
            bf16x8 a = *(const bf16x8*)(&h0s[c15 * HS + ks * 32 + q * 8]);
            #pragma unroll
            for (int g = 0; g < 3; ++g) hacc[g] = mfma16(a, fhh0[g][ks], hacc[g]);
        }
    };

    // phases 3-5 for one timestep, given its gi0 accumulators
    auto phase_tail = [&](const f32x4 (&g0)[3]) {
        __syncthreads();  // A: all waves done reading h0s (gh0)
        // --- layer-0 gates (all in registers) ---
        #pragma unroll
        for (int r = 0; r < 4; ++r) {
            float rr = sigf(g0[0][r] + bi0[0] + hacc[0][r] + bh0[0]);
            float zz = sigf(g0[1][r] + bi0[1] + hacc[1][r] + bh0[1]);
            float hn = hacc[2][r] + bh0[2];
            float nn = tanhf_(g0[2][r] + bi0[2] + rr * hn);
            float hnew = (1.f - zz) * nn + zz * h0r[r];
            h0r[r] = hnew;
            h0s[(q * 4 + r) * HS + c_col] = (__bf16)hnew;
        }
        __syncthreads();  // B: h0_new visible
        // --- layer 1: gi1 = h0_new @ Wih1^T ; gh1 = h1 @ Whh1^T ---
        f32x4 iacc[3], hacc1[3];
        #pragma unroll
        for (int g = 0; g < 3; ++g) {
            iacc[g]  = (f32x4){0.f, 0.f, 0.f, 0.f};
            hacc1[g] = (f32x4){0.f, 0.f, 0.f, 0.f};
        }
        #pragma unroll
        for (int ks = 0; ks < 4; ++ks) {
            bf16x8 a0 = *(const bf16x8*)(&h0s[c15 * HS + ks * 32 + q * 8]);
            bf16x8 a1 = *(const bf16x8*)(&h1s[c15 * HS + ks * 32 + q * 8]);
            #pragma unroll
            for (int g = 0; g < 3; ++g) {
                iacc[g]  = mfma16(a0, fih1[g][ks], iacc[g]);
                hacc1[g] = mfma16(a1, fhh1[g][ks], hacc1[g]);
            }
        }
        __syncthreads();  // C: all waves done reading h1s
        // --- layer-1 gates ---
        #pragma unroll
        for (int r = 0; r < 4; ++r) {
            float rr = sigf(iacc[0][r] + bi1[0] + hacc1[0][r] + bh1[0]);
            float zz = sigf(iacc[1][r] + bi1[1] + hacc1[1][r] + bh1[1]);
            float hn = hacc1[2][r] + bh1[2];
            float nn = tanhf_(iacc[2][r] + bi1[2] + rr * hn);
            float hnew = (1.f - zz) * nn + zz * h1r[r];
            h1r[r] = hnew;
            h1s[(q * 4 + r) * HS + c_col] = (__bf16)hnew;
        }
        // next h1s write is 2 barriers away -> no barrier needed here
    };

    for (int tt = 0; tt < 128; ++tt) {
        const int t = tt * 2;
        // ---- even timestep ----
        phase_gh0();
        {   // gi0 for t and t+1 (share Wih0 fragment loads; K=160, 5 ksteps)
            #pragma unroll
            for (int g = 0; g < 3; ++g) {
                giA[g] = (f32x4){0.f, 0.f, 0.f, 0.f};
                giB[g] = (f32x4){0.f, 0.f, 0.f, 0.f};
            }
            const __bf16* xrow0 = xb + ((size_t)(t * 1024 + b0 + c15)) * 160;
            const __bf16* xrow1 = xrow0 + 1024 * 160;
            #pragma unroll
            for (int ks = 0; ks < 5; ++ks) {
                bf16x8 a0 = *(const bf16x8*)(xrow0 + ks * 32 + q * 8);
                bf16x8 a1 = *(const bf16x8*)(xrow1 + ks * 32 + q * 8);
                #pragma unroll
                for (int g = 0; g < 3; ++g) {
                    bf16x8 bw = *(const bf16x8*)(Wih0 + (g * 128 + c_col) * 160 + ks * 32 + q * 8);
                    giA[g] = mfma16(a0, bw, giA[g]);
                    giB[g] = mfma16(a1, bw, giB[g]);
                }
            }
        }
        phase_tail(giA);
        // ---- odd timestep ----
        phase_gh0();
        phase_tail(giB);
    }

    // ---- head: relu(h1 @ W1^T + b1) @ W2^T + b2 -> sigmoid ----------------
    #pragma unroll
    for (int r = 0; r < 4; ++r) h1f[(q * 4 + r) * 128 + c_col] = h1r[r];
    __syncthreads();
    for (int p = tid; p < 16 * 64; p += 512) {
        int m = p >> 6, u = p & 63;
        float s = b1[u];
        const float* hrow = &h1f[m * 128];
        const float* wrow = &W1[u * 128];
        #pragma unroll 8
        for (int k = 0; k < 128; ++k) s += hrow[k] * wrow[k];
        hdnf[p] = fmaxf(s, 0.f);
    }
    __syncthreads();
    if (tid < 16) {
        float s = b2[0];
        #pragma unroll 8
        for (int k = 0; k < 64; ++k) s += hdnf[tid * 64 + k] * W2[k];
        out[b0 + tid] = sigf(s);
    }
}

// ---------------------------------------------------------------------------
extern "C" void kernel_launch(void* const* d_in, const int* in_sizes, int n_in,
                              void* d_out, int out_size, void* d_ws, size_t ws_size,
                              hipStream_t stream) {
    const float* x     = (const float*)d_in[0];
    const float* W_ih0 = (const float*)d_in[1];
    const float* W_hh0 = (const float*)d_in[2];
    const float* bih0  = (const float*)d_in[3];
    const float* bhh0  = (const float*)d_in[4];
    const float* W_ih1 = (const float*)d_in[5];
    const float* W_hh1 = (const float*)d_in[6];
    const float* bih1  = (const float*)d_in[7];
    const float* bhh1  = (const float*)d_in[8];
    const float* W1    = (const float*)d_in[9];
    const float* b1    = (const float*)d_in[10];
    const float* W2    = (const float*)d_in[11];
    const float* b2    = (const float*)d_in[12];
    float* out = (float*)d_out;

    char* ws = (char*)d_ws;
    // ws layout (bytes), all 16B aligned:
    //   xb    : 262144 rows x 160 bf16 = 83,886,080
    //   Wih0b : 384x160 bf16          =    122,880
    //   Whh0b / Wih1b / Whh1b : 384x128 bf16 = 98,304 each
    __bf16* xb    = (__bf16*)(ws);
    __bf16* wih0b = (__bf16*)(ws + 83886080);
    __bf16* whh0b = (__bf16*)(ws + 84008960);
    __bf16* wih1b = (__bf16*)(ws + 84107264);
    __bf16* whh1b = (__bf16*)(ws + 84205568);

    prep_w_kernel<<<240, 256, 0, stream>>>(W_ih0, W_hh0, W_ih1, W_hh1,
                                           wih0b, whh0b, wih1b, whh1b);
    cast_x_kernel<<<65536, 256, 0, stream>>>(x, xb);
    gru_fused_kernel<<<64, 512, 0, stream>>>(xb, wih0b, whh0b, wih1b, whh1b,
                                             bih0, bhh0, bih1, bhh1,
                                             W1, b1, W2, b2, out);
}